// Round 8
// baseline (183.007 us; speedup 1.0000x reference)
//
#include <hip/hip_runtime.h>
#include <hip/hip_bf16.h>

#define Bb 2
#define Ss 2048
#define Dd 1024
#define Hh 16
#define HDd 64
#define Mm (Bb*Ss)   // 4096

typedef __attribute__((ext_vector_type(8))) short short8;
typedef __attribute__((ext_vector_type(4))) float f32x4;

__device__ __forceinline__ unsigned short f2bf(float f) {
  unsigned int u = __float_as_uint(f);
  return (unsigned short)((u + 0x7FFFu + ((u >> 16) & 1u)) >> 16);
}

__device__ __forceinline__ void gload_lds16(const unsigned short* g, unsigned short* l) {
  __builtin_amdgcn_global_load_lds(
      (const __attribute__((address_space(1))) unsigned int*)g,
      (__attribute__((address_space(3))) unsigned int*)l, 16, 0, 0);
}

// Stage a ROWSx64 bf16 tile (rows contiguous, leading dim ldg) into LDS laid
// out [ROWS][64] with read-side XOR swizzle (elem ^= (row&7)<<3). Source is
// pre-swizzled so the linear global_load_lds dest ends up correct (rule #21).
template<int ROWS>
__device__ __forceinline__ void stage_tile(const unsigned short* __restrict__ g, size_t ldg,
                                           unsigned short* s, int w, int lane) {
#pragma unroll
  for (int i = 0; i < ROWS / 32; ++i) {
    int c = (i * 4 + w) * 64 + lane;          // 16B chunk id
    int row = c >> 3;
    int srcci = (lane & 7) ^ (row & 7);        // pre-swizzled source chunk
    gload_lds16(g + (size_t)row * ldg + (srcci << 3), s + (i * 4 + w) * 512);
  }
}

// ---------------- fused f32 -> bf16 convert (RNE), all 5 tensors -----------
__global__ __launch_bounds__(256) void cvt_all(
    const float* __restrict__ x,  const float* __restrict__ Wq,
    const float* __restrict__ Wk, const float* __restrict__ Wv,
    const float* __restrict__ Wo,
    unsigned short* __restrict__ xb, unsigned short* __restrict__ Wb,
    unsigned short* __restrict__ Wob) {
  int bid = blockIdx.x;
  const float* src; unsigned short* dst; int base;
  if (bid < 4096)      { src = x;  dst = xb;              base = bid; }
  else if (bid < 5120) { src = Wq; dst = Wb;              base = bid - 4096; }
  else if (bid < 6144) { src = Wk; dst = Wb + Dd * Dd;    base = bid - 5120; }
  else if (bid < 7168) { src = Wv; dst = Wb + 2 * Dd * Dd; base = bid - 6144; }
  else                 { src = Wo; dst = Wob;             base = bid - 7168; }
  int i = base * 256 + threadIdx.x;
  f32x4 v = ((const f32x4*)src)[i];
  ushort4 o;
  o.x = f2bf(v[0]); o.y = f2bf(v[1]); o.z = f2bf(v[2]); o.w = f2bf(v[3]);
  ((ushort4*)dst)[i] = o;
}

// ---------------- QKV projection, 128x128 tile, 2-phase dbuf ---------------
__global__ __launch_bounds__(256, 2) void gemm_qkv2(
    const unsigned short* __restrict__ xb,
    const unsigned short* __restrict__ Wb,   // [3][D][D], row n = out col n
    unsigned short* __restrict__ Qo,
    unsigned short* __restrict__ Ko,
    unsigned short* __restrict__ Vt) {
  __shared__ unsigned short As[2][128 * 64], Bs[2][128 * 64];
  const int lin = (int)blockIdx.x + 32 * ((int)blockIdx.y + 8 * (int)blockIdx.z);
  const int orig = (lin & 7) * 96 + (lin >> 3);     // [0,768) bijective
  const int z = orig >> 8;                           // 0..2
  const int rem = orig & 255;
  const int tm = (rem >> 3) * 128, tn = (rem & 7) * 128;
  const unsigned short* W = Wb + (size_t)z * Dd * Dd;
  const int tid = threadIdx.x, w = tid >> 6, lane = tid & 63;
  const int lrow = lane & 15, lgr = lane >> 4;
  const int wm = w >> 1, wn = w & 1;

  f32x4 acc[4][4] = {};
  stage_tile<128>(xb + (size_t)tm * Dd, Dd, As[0], w, lane);
  stage_tile<128>(W + (size_t)tn * Dd, Dd, Bs[0], w, lane);
  __syncthreads();
  for (int k = 0; k < 16; ++k) {
    const int cur = k & 1;
    if (k + 1 < 16) {
      stage_tile<128>(xb + (size_t)tm * Dd + (k + 1) * 64, Dd, As[cur ^ 1], w, lane);
      stage_tile<128>(W + (size_t)tn * Dd + (k + 1) * 64, Dd, Bs[cur ^ 1], w, lane);
    }
#pragma unroll
    for (int half = 0; half < 2; ++half) {
      short8 af[4], bf[4];
#pragma unroll
      for (int mt = 0; mt < 4; ++mt) {
        int row = wm * 64 + mt * 16 + lrow;
        int e = (row * 64 + half * 32 + 8 * lgr) ^ ((row & 7) << 3);
        af[mt] = *(const short8*)(As[cur] + e);
      }
#pragma unroll
      for (int nt = 0; nt < 4; ++nt) {
        int row = wn * 64 + nt * 16 + lrow;
        int e = (row * 64 + half * 32 + 8 * lgr) ^ ((row & 7) << 3);
        bf[nt] = *(const short8*)(Bs[cur] + e);
      }
      if (z != 2) {
#pragma unroll
        for (int mt = 0; mt < 4; ++mt)
#pragma unroll
          for (int nt = 0; nt < 4; ++nt)
            acc[mt][nt] = __builtin_amdgcn_mfma_f32_16x16x32_bf16(af[mt], bf[nt], acc[mt][nt], 0, 0, 0);
      } else {
#pragma unroll
        for (int mt = 0; mt < 4; ++mt)
#pragma unroll
          for (int nt = 0; nt < 4; ++nt)
            acc[mt][nt] = __builtin_amdgcn_mfma_f32_16x16x32_bf16(bf[nt], af[mt], acc[mt][nt], 0, 0, 0);
      }
    }
    __syncthreads();
  }

  // ---- coalesced epilogue via per-wave LDS bounce ([16][72] bf16) ----
  unsigned short* BB = &As[0][0];
  const int brow = lane & 15, bseg = lane >> 4;
  if (z < 2) {
    unsigned short* C = z ? Ko : Qo;
#pragma unroll
    for (int mt = 0; mt < 4; ++mt) {
      unsigned short* bl = BB + (w * 2 + (mt & 1)) * (16 * 72);
#pragma unroll
      for (int nt = 0; nt < 4; ++nt)
#pragma unroll
        for (int r = 0; r < 4; ++r)
          bl[(lgr * 4 + r) * 72 + nt * 16 + lrow] = f2bf(acc[mt][nt][r]);
#pragma unroll
      for (int p = 0; p < 2; ++p) {
        short8 v = *(const short8*)(bl + brow * 72 + bseg * 8 + p * 32);
        *(short8*)(C + (size_t)(tm + wm * 64 + mt * 16 + brow) * Dd
                     + tn + wn * 64 + bseg * 8 + p * 32) = v;
      }
    }
  } else {
    const int bidx = tm >> 11;
#pragma unroll
    for (int nt = 0; nt < 4; ++nt) {
      unsigned short* bl = BB + (w * 2 + (nt & 1)) * (16 * 72);
#pragma unroll
      for (int mt = 0; mt < 4; ++mt)
#pragma unroll
        for (int r = 0; r < 4; ++r)
          bl[(lgr * 4 + r) * 72 + mt * 16 + lrow] = f2bf(acc[mt][nt][r]);
      int n = tn + wn * 64 + nt * 16 + brow;
      int h = n >> 6, hd = n & (HDd - 1);
#pragma unroll
      for (int p = 0; p < 2; ++p) {
        short8 v = *(const short8*)(bl + brow * 72 + bseg * 8 + p * 32);
        int sbase = (tm & (Ss - 1)) + wm * 64 + bseg * 8 + p * 32;
        *(short8*)(Vt + ((size_t)(bidx * Hh + h) * HDd + hd) * Ss + sbase) = v;
      }
    }
  }
}

// ---------------- Flash causal attention, uniform-33 two-phase -------------
// Fixed-reference exp2 softmax => partial results are ADDITIVE, so each block
// processes the q-tile PAIR (u, 31-u) sequentially: exactly 33 kv-iters for
// EVERY block -> zero completion-time tail. 512 blocks, 2/CU, 8 waves/CU.
// XCD remap keeps 4 consecutive heads per XCD (K/V hot set 2MB in L2).
#define SC2 0.18033688011f
__global__ __launch_bounds__(256) void attn6(
    const unsigned short* __restrict__ Q,
    const unsigned short* __restrict__ K,
    const unsigned short* __restrict__ Vt,
    unsigned short* __restrict__ att) {
  __shared__ unsigned short Ks[2][64 * 64];   // [key][hd], swizzled
  __shared__ unsigned short Vs[2][64 * 64];   // [hd][s],  swizzled
  __shared__ unsigned short Ps[4][16 * 64];   // per-wave P tile

  const int lin = (int)blockIdx.x + 16 * (int)blockIdx.y;   // grid (16,32)
  const int orig = (lin & 7) * 64 + (lin >> 3);             // [0,512) bijective
  const int bhp = orig >> 4, up = orig & 15;
  const int b = bhp >> 4, h = bhp & (Hh - 1);
  const int tid = threadIdx.x, w = tid >> 6, lane = tid & 63;
  const int lrow = lane & 15, lgr = lane >> 4;

  const unsigned short* Kbase = K + (size_t)(b * Ss) * Dd + h * HDd;   // row=key, ldg=Dd
  const unsigned short* Vbase = Vt + (size_t)(b * Hh + h) * HDd * Ss;  // row=hd,  ldg=Ss
  const short8 vones = {0x3F80, 0x3F80, 0x3F80, 0x3F80, 0x3F80, 0x3F80, 0x3F80, 0x3F80};

  for (int ph = 0; ph < 2; ++ph) {
    const int qb = ph ? (31 - up) : up;
    const int qbase = qb * 64 + w * 16;
    const int nkv = qb + 1;

    const unsigned short* qp = Q + (size_t)(b * Ss + qbase + lrow) * Dd + h * HDd + 8 * lgr;
    short8 aq0 = *(const short8*)qp;
    short8 aq1 = *(const short8*)(qp + 32);

    f32x4 pacc[4] = {};
    f32x4 lacc = {};

    stage_tile<64>(Kbase, Dd, Ks[0], w, lane);
    stage_tile<64>(Vbase, Ss, Vs[0], w, lane);
    __syncthreads();

    for (int kvb = 0; kvb < nkv; ++kvb) {
      const int cur = kvb & 1;
      if (kvb + 1 < nkv) {   // prefetch next tile into the other buffer
        stage_tile<64>(Kbase + (size_t)(kvb + 1) * 64 * Dd, Dd, Ks[cur ^ 1], w, lane);
        stage_tile<64>(Vbase + (size_t)(kvb + 1) * 64, Ss, Vs[cur ^ 1], w, lane);
      }
      // ---- S = Q K^T from LDS ----
      f32x4 sacc[4] = {};
      __builtin_amdgcn_s_setprio(1);
#pragma unroll
      for (int nt = 0; nt < 4; ++nt) {
        int row = nt * 16 + lrow;
        int e0 = (row * 64 + 8 * lgr) ^ ((row & 7) << 3);
        int e1 = (row * 64 + 32 + 8 * lgr) ^ ((row & 7) << 3);
        short8 bk0 = *(const short8*)(Ks[cur] + e0);
        short8 bk1 = *(const short8*)(Ks[cur] + e1);
        sacc[nt] = __builtin_amdgcn_mfma_f32_16x16x32_bf16(aq0, bk0, sacc[nt], 0, 0, 0);
        sacc[nt] = __builtin_amdgcn_mfma_f32_16x16x32_bf16(aq1, bk1, sacc[nt], 0, 0, 0);
      }
      __builtin_amdgcn_s_setprio(0);
      // ---- p = exp2(s*SC2), mask only on diagonal block ----
      if (kvb < qb) {
#pragma unroll
        for (int nt = 0; nt < 4; ++nt)
#pragma unroll
          for (int r = 0; r < 4; ++r)
            sacc[nt][r] = __builtin_amdgcn_exp2f(sacc[nt][r] * SC2);
      } else {
#pragma unroll
        for (int r = 0; r < 4; ++r) {
          int qg = qbase + lgr * 4 + r;
#pragma unroll
          for (int nt = 0; nt < 4; ++nt) {
            int kg = kvb * 64 + nt * 16 + lrow;
            float tt = sacc[nt][r] * SC2;
            sacc[nt][r] = (kg <= qg) ? __builtin_amdgcn_exp2f(tt) : 0.f;
          }
        }
      }
      // ---- P -> wave-private LDS (XOR swizzle, trunc bf16), no barrier ----
      unsigned short* pl = Ps[w];
#pragma unroll
      for (int nt = 0; nt < 4; ++nt)
#pragma unroll
        for (int r = 0; r < 4; ++r) {
          int row = lgr * 4 + r, col = nt * 16 + lrow;
          int byteoff = (row * 128 + col * 2) ^ ((row & 7) << 4);
          *(unsigned short*)((char*)pl + byteoff) =
              (unsigned short)(__float_as_uint(sacc[nt][r]) >> 16);
        }
      short8 apv[2];
#pragma unroll
      for (int ks = 0; ks < 2; ++ks) {
        int byteoff = (lrow * 128 + (ks * 32 + 8 * lgr) * 2) ^ ((lrow & 7) << 4);
        apv[ks] = *(const short8*)((char*)pl + byteoff);
      }
      // ---- PV from LDS V tile + row-sum via ones-MFMA ----
      __builtin_amdgcn_s_setprio(1);
#pragma unroll
      for (int nt = 0; nt < 4; ++nt) {
        int row = nt * 16 + lrow;
        int e0 = (row * 64 + 8 * lgr) ^ ((row & 7) << 3);
        int e1 = (row * 64 + 32 + 8 * lgr) ^ ((row & 7) << 3);
        short8 bv0 = *(const short8*)(Vs[cur] + e0);
        short8 bv1 = *(const short8*)(Vs[cur] + e1);
        pacc[nt] = __builtin_amdgcn_mfma_f32_16x16x32_bf16(apv[0], bv0, pacc[nt], 0, 0, 0);
        pacc[nt] = __builtin_amdgcn_mfma_f32_16x16x32_bf16(apv[1], bv1, pacc[nt], 0, 0, 0);
      }
      lacc = __builtin_amdgcn_mfma_f32_16x16x32_bf16(apv[0], vones, lacc, 0, 0, 0);
      lacc = __builtin_amdgcn_mfma_f32_16x16x32_bf16(apv[1], vones, lacc, 0, 0, 0);
      __builtin_amdgcn_s_setprio(0);
      __syncthreads();   // drains vmcnt (prefetch landed) + lgkm
    }
    // ---- epilogue: normalize by l = ones-MFMA rowsum ----
    float inv[4];
#pragma unroll
    for (int r = 0; r < 4; ++r) inv[r] = 1.f / lacc[r];
#pragma unroll
    for (int nt = 0; nt < 4; ++nt)
#pragma unroll
      for (int r = 0; r < 4; ++r) {
        int qg = qbase + lgr * 4 + r;
        att[(size_t)(b * Ss + qg) * Dd + h * HDd + nt * 16 + lrow] = f2bf(pacc[nt][r] * inv[r]);
      }
    __syncthreads();  // all waves done with K/V bufs before next phase restages
  }
}

// ---------------- Output projection: 128x64 tile, 2-phase dbuf, f32 out ----
__global__ __launch_bounds__(256, 3) void gemm_o2(
    const unsigned short* __restrict__ att,
    const unsigned short* __restrict__ Wob,
    float* __restrict__ out) {
  __shared__ unsigned short As[2][128 * 64], Bs[2][64 * 64];
  const int lin = (int)blockIdx.x + 32 * (int)blockIdx.y;   // grid (32,16)
  const int orig = (lin & 7) * 64 + (lin >> 3);             // [0,512)
  const int tm = (orig >> 4) * 128, tn = (orig & 15) * 64;
  const int tid = threadIdx.x, w = tid >> 6, lane = tid & 63;
  const int lrow = lane & 15, lgr = lane >> 4;
  const int wm = w >> 1, wn = w & 1;

  f32x4 acc[4][2] = {};
  stage_tile<128>(att + (size_t)tm * Dd, Dd, As[0], w, lane);
  stage_tile<64>(Wob + (size_t)tn * Dd, Dd, Bs[0], w, lane);
  __syncthreads();
  for (int k = 0; k < 16; ++k) {
    const int cur = k & 1;
    if (k + 1 < 16) {
      stage_tile<128>(att + (size_t)tm * Dd + (k + 1) * 64, Dd, As[cur ^ 1], w, lane);
      stage_tile<64>(Wob + (size_t)tn * Dd + (k + 1) * 64, Dd, Bs[cur ^ 1], w, lane);
    }
#pragma unroll
    for (int half = 0; half < 2; ++half) {
      short8 af[4], bf[2];
#pragma unroll
      for (int mt = 0; mt < 4; ++mt) {
        int row = wm * 64 + mt * 16 + lrow;
        int e = (row * 64 + half * 32 + 8 * lgr) ^ ((row & 7) << 3);
        af[mt] = *(const short8*)(As[cur] + e);
      }
#pragma unroll
      for (int nt = 0; nt < 2; ++nt) {
        int row = wn * 32 + nt * 16 + lrow;
        int e = (row * 64 + half * 32 + 8 * lgr) ^ ((row & 7) << 3);
        bf[nt] = *(const short8*)(Bs[cur] + e);
      }
#pragma unroll
      for (int mt = 0; mt < 4; ++mt)
#pragma unroll
        for (int nt = 0; nt < 2; ++nt)
          acc[mt][nt] = __builtin_amdgcn_mfma_f32_16x16x32_bf16(af[mt], bf[nt], acc[mt][nt], 0, 0, 0);
    }
    __syncthreads();
  }
  // ---- coalesced f32 epilogue via per-wave LDS bounce ([16][36] f32) ----
  const int brow = lane & 15, bseg = lane >> 4;
#pragma unroll
  for (int mt = 0; mt < 4; ++mt) {
    float* blf = ((float*)&As[0][0]) + (w * 2 + (mt & 1)) * (16 * 36);
#pragma unroll
    for (int nt = 0; nt < 2; ++nt)
#pragma unroll
      for (int r = 0; r < 4; ++r)
        blf[(lgr * 4 + r) * 36 + nt * 16 + lrow] = acc[mt][nt][r];
#pragma unroll
    for (int p = 0; p < 2; ++p) {
      f32x4 v = *(const f32x4*)(blf + brow * 36 + bseg * 4 + p * 16);
      *(f32x4*)(out + (size_t)(tm + wm * 64 + mt * 16 + brow) * Dd
                   + tn + wn * 32 + bseg * 4 + p * 16) = v;
    }
  }
}

extern "C" void kernel_launch(void* const* d_in, const int* in_sizes, int n_in,
                              void* d_out, int out_size, void* d_ws, size_t ws_size,
                              hipStream_t stream) {
  const float* x  = (const float*)d_in[0];
  const float* Wq = (const float*)d_in[1];
  const float* Wk = (const float*)d_in[2];
  const float* Wv = (const float*)d_in[3];
  const float* Wo = (const float*)d_in[4];

  char* ws = (char*)d_ws;
  unsigned short* xb  = (unsigned short*)(ws);                       // 8 MB [M][D]
  unsigned short* Wb  = (unsigned short*)(ws + (8u  << 20));         // 6 MB [3][D][D]
  unsigned short* Wob = (unsigned short*)(ws + (14u << 20));         // 2 MB
  unsigned short* Qb  = (unsigned short*)(ws + (16u << 20));         // 8 MB
  unsigned short* Kb  = (unsigned short*)(ws + (24u << 20));         // 8 MB
  unsigned short* Vt  = (unsigned short*)(ws + (32u << 20));         // 8 MB
  unsigned short* att = xb;  // xb dead after gemm_qkv2

  cvt_all<<<8192, 256, 0, stream>>>(x, Wq, Wk, Wv, Wo, xb, Wb, Wob);
  gemm_qkv2<<<dim3(Mm / 128, Dd / 128, 3), 256, 0, stream>>>(xb, Wb, Qb, Kb, Vt);
  attn6<<<dim3(16, 32), 256, 0, stream>>>(Qb, Kb, Vt, att);
  gemm_o2<<<dim3(Mm / 128, Dd / 64), 256, 0, stream>>>(att, Wob, (float*)d_out);
}